// Round 7
// baseline (221.236 us; speedup 1.0000x reference)
//
#include <hip/hip_runtime.h>

typedef _Float16 f16;
typedef _Float16 f16x8 __attribute__((ext_vector_type(8)));
typedef float    f32x4 __attribute__((ext_vector_type(4)));

#define AS3 __attribute__((address_space(3)))
#define AS1 __attribute__((address_space(1)))

// async global->LDS, 16B per lane. LDS dest = wave-uniform base + lane*16.
static __device__ __forceinline__ void gld_lds16(const f16* g, f16* l) {
    __builtin_amdgcn_global_load_lds((const AS1 void*)g, (AS3 void*)l, 16, 0, 0);
}

// ---------------- fused converts (one launch) ----------------
__global__ void cvt_fused(const float* __restrict__ x, f16* __restrict__ xh,
                          const float* __restrict__ Wq, const float* __restrict__ Wk,
                          const float* __restrict__ Wv, f16* __restrict__ Wt) {
    __shared__ float tile[32][33];
    const int bid = blockIdx.x;
    if (bid < 4096) {
        int i = bid * 256 + threadIdx.x;
        const f32x4* xv = (const f32x4*)x;
        f32x4 a = xv[2 * i], b = xv[2 * i + 1];
        f16x8 h;
        h[0] = (f16)a[0]; h[1] = (f16)a[1]; h[2] = (f16)a[2]; h[3] = (f16)a[3];
        h[4] = (f16)b[0]; h[5] = (f16)b[1]; h[6] = (f16)b[2]; h[7] = (f16)b[3];
        ((f16x8*)xh)[i] = h;
    } else {
        int b2 = bid - 4096;
        int bx = b2 & 31, by = (b2 >> 5) & 31, bz = b2 >> 10;
        const float* W = bz == 0 ? Wq : (bz == 1 ? Wk : Wv);
        int tx = threadIdx.x & 31, ty = threadIdx.x >> 5;   // 32 x 8
        int n0 = bx * 32, k0 = by * 32;
#pragma unroll
        for (int r = 0; r < 4; ++r)
            tile[ty + r * 8][tx] = W[(size_t)(k0 + ty + r * 8) * 1024 + n0 + tx];
        __syncthreads();
        f16* o = Wt + (size_t)bz * 1024 * 1024;
#pragma unroll
        for (int r = 0; r < 4; ++r)
            o[(size_t)(n0 + ty + r * 8) * 1024 + k0 + tx] = (f16)tile[tx][ty + r * 8];
    }
}

// ============ 256x256 8-phase GEMM (T3+T4+T5): QK projection ONLY ============
// grid = exactly 256 blocks (32 m-tiles x 8 n-tiles) -> one clean dispatch
// wave at 1 block/CU (128 KiB LDS). XCD remap: XCD c gets all 8 n-tiles of
// m-tiles 4c..4c+3 -> whole 4 MB W panel set L2-resident per XCD.
// Schedule/swizzle verified round-3 (0 bank conflicts).
#define KT 16

__global__ __launch_bounds__(512, 2)
void gemm256(const f16* __restrict__ Axh, const f16* __restrict__ Bw, f16* __restrict__ Cqk) {
    const int orig = blockIdx.x;
    const int wg = (orig & 7) * 32 + (orig >> 3);   // 256 % 8 == 0 -> bijective
    const int m0 = (wg >> 3) * 256, n0 = (wg & 7) * 256;
    const f16* Ab = Axh; const f16* Bb = Bw; f16* Cb = Cqk;
    const int lda = 1024, ldb = 1024, ldc = 2048;

    __shared__ f16 lds[2 * 32768];       // 128 KiB

    const int tid = threadIdx.x;
    const int wave = tid >> 6, lane = tid & 63;
    const int q = lane >> 4, rr = lane & 15;
    const int wr = wave >> 2, wc = wave & 3;

    const int kcs = (((lane & 7) - (lane >> 3)) & 7) * 8;   // f16 col in BK=64
    const f16* pA = Ab + (long)(m0 + (tid >> 3)) * lda + kcs;
    const f16* pB = Bb + (long)(n0 + (tid >> 3)) * ldb + kcs;
    const int ldsw = wave * 512;         // wave-uniform dest; HW adds lane*16B

    auto stageA = [&](int kt, int h, int buf) {
        f16* dst = lds + buf * 32768 + h * 8192 + ldsw;
        const f16* src = pA + (long)(h * 128) * lda + kt * 64;
        gld_lds16(src, dst);
        gld_lds16(src + (long)64 * lda, dst + 4096);
    };
    auto stageB = [&](int kt, int h, int buf) {
        f16* dst = lds + buf * 32768 + 16384 + h * 8192 + ldsw;
        const f16* src = pB + (long)(h * 128) * ldb + kt * 64;
        gld_lds16(src, dst);
        gld_lds16(src + (long)64 * ldb, dst + 4096);
    };

    f32x4 acc[8][4] = {};

    // prologue: tile0 all 4 halves + tile1.B0/B1; vmcnt(4) -> tile0 landed.
    stageA(0, 0, 0); stageA(0, 1, 0); stageB(0, 0, 0); stageB(0, 1, 0);
    stageB(1, 0, 1); stageB(1, 1, 1);
    asm volatile("s_waitcnt vmcnt(4)" ::: "memory");
    __builtin_amdgcn_s_barrier();

    for (int u = 0; u < KT; ++u) {
        const int cur = u & 1;
        const f16* bA = lds + cur * 32768 + wr * 8192;
        const f16* bB = lds + cur * 32768 + 16384 + (wc >> 1) * 8192;
        const int brow = (wc & 1) * 64;
        const int ua = u + 1 < KT ? u + 1 : KT - 1;     // clamp: keep counts uniform
        const int ub = u + 2 < KT ? u + 2 : KT - 1;
        const int bufA_ = (u + 1) & 1, bufB_ = cur;     // (u+2)&1 == u&1
        f16x8 bf[4][2];
#pragma unroll
        for (int p = 0; p < 4; ++p) {
            f16x8 a[2][2];
            if (p == 0) {
#pragma unroll
                for (int j = 0; j < 4; ++j)
#pragma unroll
                    for (int ks = 0; ks < 2; ++ks)
                        bf[j][ks] = *(const f16x8*)&bB[(brow + j * 16 + rr) * 64 + ((ks * 4 + q + rr) & 7) * 8];
            }
#pragma unroll
            for (int fi = 0; fi < 2; ++fi)
#pragma unroll
                for (int ks = 0; ks < 2; ++ks)
                    a[fi][ks] = *(const f16x8*)&bA[((p * 2 + fi) * 16 + rr) * 64 + ((ks * 4 + q + rr) & 7) * 8];
            if      (p == 0) stageA(ua, 0, bufA_);
            else if (p == 1) stageA(ua, 1, bufA_);
            else if (p == 2) stageB(ub, 0, bufB_);
            else             stageB(ub, 1, bufB_);
            __builtin_amdgcn_s_barrier();
            asm volatile("s_waitcnt lgkmcnt(0)" ::: "memory");
            __builtin_amdgcn_sched_barrier(0);
            __builtin_amdgcn_s_setprio(1);
#pragma unroll
            for (int ks = 0; ks < 2; ++ks)
#pragma unroll
                for (int fi = 0; fi < 2; ++fi)
#pragma unroll
                    for (int j = 0; j < 4; ++j)
                        acc[p * 2 + fi][j] = __builtin_amdgcn_mfma_f32_16x16x32_f16(
                            a[fi][ks], bf[j][ks], acc[p * 2 + fi][j], 0, 0, 0);
            __builtin_amdgcn_s_setprio(0);
            if (p == 3) asm volatile("s_waitcnt vmcnt(4)" ::: "memory");
            __builtin_amdgcn_s_barrier();
        }
    }
    asm volatile("s_waitcnt vmcnt(0)" ::: "memory");     // drain DMA before exit

    // epilogue: row = m0 + wr*128 + i*16 + q*4 + r2, col = n0 + wc*64 + j*16 + rr
#pragma unroll
    for (int i = 0; i < 8; ++i)
#pragma unroll
        for (int r2 = 0; r2 < 4; ++r2) {
            const long row = m0 + wr * 128 + i * 16 + q * 4 + r2;
#pragma unroll
            for (int j = 0; j < 4; ++j)
                Cb[row * ldc + n0 + wc * 64 + j * 16 + rr] = (f16)acc[i][j][r2];
        }
}

// -------- 128x128 MFMA GEMM, 4 waves, XOR-swizzled k-chunks --------
// Counted-vmcnt 3-buffer pipeline (verified round-6): stage kt+2, compute
// kt%3, vmcnt(4)+s_barrier per K-step, no in-loop drain. LDS 48KB, 3 blk/CU.
// MODE 1: grid (264,1,4). NEW: XCD map row-matched to MODE 2 for the P
//         L2-handoff. XCD c (= blockIdx.x & 7; 264%8==0, bz-independent):
//           w = x>>3 in [0,33)
//           w<17 : triangle rows {c, 15-c}: w<=c -> (bm,bn)=(c,w)
//                  else (15-c, w-c-1).  (c+1)+(16-c)=17 blocks, uniform.
//           w>=17: V^T h-panel mh=c, t-tile w-17: Wv^T panel (256KB)
//                  L2-resident per XCD.
//         P rows {c,15-c} (2.2MB/XCD over 4 bz) are then READ by the same
//         XCD in MODE 2 -> L2 handoff instead of HBM round-trip.
// MODE 2: grid (8,16,4), XCD c <- rows {c,15-c}, long/short complementary
//         across the co-resident (bz,bz+2) pair -> 68 ktiles on every CU.
//         Row sums in-kernel via ones-MFMA on wn==0 waves; f32 scalar stores.
template <int MODE>
__global__ __launch_bounds__(256, 3)
void gemm128(const f16* __restrict__ A, int lda, long aStride,
             const f16* __restrict__ B, int ldb, long bStride,
             void* __restrict__ Cout, int ldc, long cStride,
             int ktiles, float scale,
             const f16* __restrict__ A2, const f16* __restrict__ B2,
             void* __restrict__ C2) {
    int bz = blockIdx.z;
    int m0, n0;
    const f16 *Ab, *Bb;
    char* Cb;
    bool proj = false;

    if (MODE == 1) {
        int x = blockIdx.x;
        int c = x & 7, w = x >> 3;           // XCD c, work item w in [0,33)
        if (w < 17) {                        // triangle rows {c, 15-c}
            int bm = (w <= c) ? c : 15 - c;
            int bn = (w <= c) ? w : w - c - 1;
            m0 = bm * 128; n0 = bn * 128;
            Ab = A + (long)bz * aStride;
            Bb = B + (long)bz * bStride;
            Cb = (char*)Cout + (long)bz * cStride * sizeof(f16);
        } else {                             // V^T: Vt[b][h][t], h-panel = c
            proj = true;
            m0 = c * 128;                    // h-tile (8, = XCD)
            n0 = (w - 17) * 128;             // t-tile (16)
            Ab = A2;                         // Wv^T rows, ld 1024
            Bb = B2 + (long)bz * 2048 * 1024;
            Cb = (char*)C2 + (long)bz * 1024 * 2048 * sizeof(f16);
            lda = 1024; ldb = 1024; ldc = 2048;
        }
    } else {
        int l = blockIdx.x + 8 * blockIdx.y; // grid (8,16): l in [0,128)
        int c = l & 7, idx = l >> 3;
        int bm = ((idx < 8) ^ (bz >= 2)) ? (15 - c) : c;   // complementary pair
        int bn = idx & 7;
        int lim = 4 * (bm + 1); if (lim < ktiles) ktiles = lim;
        m0 = bm * 128; n0 = bn * 128;
        Ab = A + (long)bz * aStride;
        Bb = B + (long)bz * bStride;
        Cb = (char*)Cout + (long)bz * cStride * sizeof(float);
    }

    __shared__ f16 lds[3 * 8192];    // 3 x [A:4096 f16 | B:4096 f16] = 48 KiB

    const int tid = threadIdx.x;
    const int wave = tid >> 6, lane = tid & 63;
    const int q = lane >> 4, rr = lane & 15;
    const int wm = (wave >> 1) * 64, wn = (wave & 1) * 64;

    const int kcs = (((tid & 3) - (lane >> 4)) & 3) * 8;   // f16 col within BK=32
    const f16* pA = Ab + (long)(m0 + (tid >> 2)) * lda + kcs;
    const f16* pB = Bb + (long)(n0 + (tid >> 2)) * ldb + kcs;

    auto stage = [&](int kt, int buf) {
        const int k0 = kt * 32;
        f16* lA = lds + buf * 8192 + wave * 512;           // + lane*16B by HW
        f16* lB = lds + buf * 8192 + 4096 + wave * 512;
#pragma unroll
        for (int it = 0; it < 2; ++it) {
            gld_lds16(pA + (long)it * 64 * lda + k0, lA + it * 2048);
            gld_lds16(pB + (long)it * 64 * ldb + k0, lB + it * 2048);
        }
    };

    const int slotf = ((q + (rr >> 2)) & 3) * 8;           // f16 col within row

    f32x4 acc[4][4] = {};
    f32x4 accs[4] = {};              // MODE 2: row sums (wn==0 waves only)
    f16x8 onef;
    const bool sumwave = (MODE == 2) && (wn == 0);
    if (MODE == 2) {
#pragma unroll
        for (int t = 0; t < 8; ++t) onef[t] = (f16)1.0f;
    }

    // prologue: tiles 0,1 in flight; vmcnt(4) -> tile0 landed (tile1's 4 fly).
    stage(0, 0);
    stage(1, 1);
    asm volatile("s_waitcnt vmcnt(4)" ::: "memory");
    __builtin_amdgcn_s_barrier();

    for (int kt = 0; kt < ktiles; ++kt) {
        const int cur = kt % 3;
        int nxt = kt + 2; if (nxt >= ktiles) nxt = ktiles - 1;  // clamp source
        stage(nxt, (kt + 2) % 3);    // issue BEFORE compute; 4 loads, uniform
        const f16* bufA = lds + cur * 8192;
        const f16* bufB = bufA + 4096;
        f16x8 af[4], bf[4];
#pragma unroll
        for (int i = 0; i < 4; ++i)
            af[i] = *(const f16x8*)&bufA[(wm + i * 16 + rr) * 32 + slotf];
#pragma unroll
        for (int j = 0; j < 4; ++j)
            bf[j] = *(const f16x8*)&bufB[(wn + j * 16 + rr) * 32 + slotf];
#pragma unroll
        for (int i = 0; i < 4; ++i) {
#pragma unroll
            for (int j = 0; j < 4; ++j)
                acc[i][j] = __builtin_amdgcn_mfma_f32_16x16x32_f16(af[i], bf[j], acc[i][j], 0, 0, 0);
            if (sumwave)             // wave-uniform branch: row sums of A (=P')
                accs[i] = __builtin_amdgcn_mfma_f32_16x16x32_f16(af[i], onef, accs[i], 0, 0, 0);
        }
        // tile kt+1's 4 loads landed; tile kt+2's 4 stay in flight. No drain.
        asm volatile("s_waitcnt vmcnt(4)" ::: "memory");
        __builtin_amdgcn_s_barrier();
    }
    asm volatile("s_waitcnt vmcnt(0)" ::: "memory");     // drain before LDS reuse/exit
    __builtin_amdgcn_s_barrier();

    // MODE 2: hand row sums to the wn==64 waves via LDS.
    float invr[4][4];
    if (MODE == 2) {
        float* rs = (float*)lds;     // 128 floats, local rows
        if (sumwave && rr == 0) {
#pragma unroll
            for (int i = 0; i < 4; ++i)
#pragma unroll
                for (int r2 = 0; r2 < 4; ++r2)
                    rs[wm + i * 16 + q * 4 + r2] = accs[i][r2];
        }
        __syncthreads();
#pragma unroll
        for (int i = 0; i < 4; ++i)
#pragma unroll
            for (int r2 = 0; r2 < 4; ++r2)
                invr[i][r2] = 1.0f / rs[wm + i * 16 + q * 4 + r2];
    }

    const float scl = (MODE == 1 && proj) ? 1.0f : scale;

    // epilogue: C/D layout col=lane&15, row=(lane>>4)*4+reg; scalar stores
#pragma unroll
    for (int i = 0; i < 4; ++i) {
#pragma unroll
        for (int r2 = 0; r2 < 4; ++r2) {
            const int row = wm + i * 16 + q * 4 + r2;       // local 0..127
#pragma unroll
            for (int j = 0; j < 4; ++j) {
                const int col = wn + j * 16 + rr;           // local 0..127
                float v = acc[i][j][r2] * scl;
                long idx = (long)(m0 + row) * ldc + n0 + col;
                if (MODE == 1) {
                    if (!proj) {
                        v = __expf(v);
                        if (n0 + col > m0 + row) v = 0.f;
                    }
                    ((f16*)Cb)[idx] = (f16)v;
                } else {
                    ((float*)Cb)[idx] = v * invr[i][r2];
                }
            }
        }
    }
}

// ---------------- launch ----------------
extern "C" void kernel_launch(void* const* d_in, const int* in_sizes, int n_in,
                              void* d_out, int out_size, void* d_ws, size_t ws_size,
                              hipStream_t stream) {
    (void)in_sizes; (void)n_in; (void)out_size; (void)ws_size;
    const float* x  = (const float*)d_in[0];
    const float* Wk = (const float*)d_in[1];
    const float* Wq = (const float*)d_in[2];
    const float* Wv = (const float*)d_in[3];
    float* out = (float*)d_out;

    const long MB = 1l << 20;
    char* ws = (char*)d_ws;
    f16*   qk   = (f16*)(ws);             // 32 MB: [4*2048][2048]  (Q cols 0-1023 | K cols 1024-2047)
    f16*   Vt   = (f16*)(ws + 32 * MB);   // 16 MB: [4][1024][2048] (V^T)
    f16*   P    = (f16*)(ws + 48 * MB);   // 32 MB: [4][2048][2048] unnormalized exp-scores
    f16*   xh   = (f16*)(ws + 81 * MB);   // 16 MB
    f16*   Wt   = (f16*)(ws + 97 * MB);   //  6 MB

    // converts, one launch
    cvt_fused<<<7168, 256, 0, stream>>>(x, xh, Wq, Wk, Wv, Wt);

    // QK projection, 256^2 8-phase, exactly 256 blocks (no dispatch tail)
    gemm256<<<dim3(256), 512, 0, stream>>>(xh, Wt, qk);

    // P' = exp(Q K^T / 32) causal-zeroed (triangle, XCD rows {c,15-c}) + V^T
    // (h-panel per XCD) per batch, one dispatch
    gemm128<1><<<dim3(264, 1, 4), 256, 0, stream>>>(qk, 2048, 2048l * 2048,
                                                    qk + 1024, 2048, 2048l * 2048,
                                                    P, 2048, 2048l * 2048, 32, 0.03125f,
                                                    Wt + 2l * 1024 * 1024, xh, Vt);
    // O = (P' V) / rowsum   (rowsum via in-kernel ones-MFMA; k clamped per row-block)
    gemm128<2><<<dim3(8, 16, 4), 256, 0, stream>>>(P, 2048, 2048l * 2048,
                                                   Vt, 2048, 1024l * 2048,
                                                   out, 1024, 2048l * 1024, 64, 1.0f,
                                                   nullptr, nullptr, nullptr);
}

// Round 10
// 215.377 us; speedup vs baseline: 1.0272x; 1.0272x over previous
//
#include <hip/hip_runtime.h>

typedef _Float16 f16;
typedef _Float16 f16x8 __attribute__((ext_vector_type(8)));
typedef float    f32x4 __attribute__((ext_vector_type(4)));

#define AS3 __attribute__((address_space(3)))
#define AS1 __attribute__((address_space(1)))

// async global->LDS, 16B per lane. LDS dest = wave-uniform base + lane*16.
static __device__ __forceinline__ void gld_lds16(const f16* g, f16* l) {
    __builtin_amdgcn_global_load_lds((const AS1 void*)g, (AS3 void*)l, 16, 0, 0);
}

// ---------------- fused converts (one launch) ----------------
__global__ void cvt_fused(const float* __restrict__ x, f16* __restrict__ xh,
                          const float* __restrict__ Wq, const float* __restrict__ Wk,
                          const float* __restrict__ Wv, f16* __restrict__ Wt) {
    __shared__ float tile[32][33];
    const int bid = blockIdx.x;
    if (bid < 4096) {
        int i = bid * 256 + threadIdx.x;
        const f32x4* xv = (const f32x4*)x;
        f32x4 a = xv[2 * i], b = xv[2 * i + 1];
        f16x8 h;
        h[0] = (f16)a[0]; h[1] = (f16)a[1]; h[2] = (f16)a[2]; h[3] = (f16)a[3];
        h[4] = (f16)b[0]; h[5] = (f16)b[1]; h[6] = (f16)b[2]; h[7] = (f16)b[3];
        ((f16x8*)xh)[i] = h;
    } else {
        int b2 = bid - 4096;
        int bx = b2 & 31, by = (b2 >> 5) & 31, bz = b2 >> 10;
        const float* W = bz == 0 ? Wq : (bz == 1 ? Wk : Wv);
        int tx = threadIdx.x & 31, ty = threadIdx.x >> 5;   // 32 x 8
        int n0 = bx * 32, k0 = by * 32;
#pragma unroll
        for (int r = 0; r < 4; ++r)
            tile[ty + r * 8][tx] = W[(size_t)(k0 + ty + r * 8) * 1024 + n0 + tx];
        __syncthreads();
        f16* o = Wt + (size_t)bz * 1024 * 1024;
#pragma unroll
        for (int r = 0; r < 4; ++r)
            o[(size_t)(n0 + ty + r * 8) * 1024 + k0 + tx] = (f16)tile[tx][ty + r * 8];
    }
}

// ============ 256x256 8-phase GEMM (T3+T4+T5): QK projection ONLY ============
// grid = exactly 256 blocks (32 m-tiles x 8 n-tiles), 1 block/CU, packed.
// XCD remap: XCD c gets all 8 n-tiles of m-tiles 4c..4c+3.
#define KT 16

__global__ __launch_bounds__(512, 2)
void gemm256(const f16* __restrict__ Axh, const f16* __restrict__ Bw, f16* __restrict__ Cqk) {
    const int orig = blockIdx.x;
    const int wg = (orig & 7) * 32 + (orig >> 3);   // 256 % 8 == 0 -> bijective
    const int m0 = (wg >> 3) * 256, n0 = (wg & 7) * 256;
    const f16* Ab = Axh; const f16* Bb = Bw; f16* Cb = Cqk;
    const int lda = 1024, ldb = 1024, ldc = 2048;

    __shared__ f16 lds[2 * 32768];       // 128 KiB

    const int tid = threadIdx.x;
    const int wave = tid >> 6, lane = tid & 63;
    const int q = lane >> 4, rr = lane & 15;
    const int wr = wave >> 2, wc = wave & 3;

    const int kcs = (((lane & 7) - (lane >> 3)) & 7) * 8;   // f16 col in BK=64
    const f16* pA = Ab + (long)(m0 + (tid >> 3)) * lda + kcs;
    const f16* pB = Bb + (long)(n0 + (tid >> 3)) * ldb + kcs;
    const int ldsw = wave * 512;         // wave-uniform dest; HW adds lane*16B

    auto stageA = [&](int kt, int h, int buf) {
        f16* dst = lds + buf * 32768 + h * 8192 + ldsw;
        const f16* src = pA + (long)(h * 128) * lda + kt * 64;
        gld_lds16(src, dst);
        gld_lds16(src + (long)64 * lda, dst + 4096);
    };
    auto stageB = [&](int kt, int h, int buf) {
        f16* dst = lds + buf * 32768 + 16384 + h * 8192 + ldsw;
        const f16* src = pB + (long)(h * 128) * ldb + kt * 64;
        gld_lds16(src, dst);
        gld_lds16(src + (long)64 * ldb, dst + 4096);
    };

    f32x4 acc[8][4] = {};

    // prologue: tile0 all 4 halves + tile1.B0/B1; vmcnt(4) -> tile0 landed.
    stageA(0, 0, 0); stageA(0, 1, 0); stageB(0, 0, 0); stageB(0, 1, 0);
    stageB(1, 0, 1); stageB(1, 1, 1);
    asm volatile("s_waitcnt vmcnt(4)" ::: "memory");
    __builtin_amdgcn_s_barrier();

    for (int u = 0; u < KT; ++u) {
        const int cur = u & 1;
        const f16* bA = lds + cur * 32768 + wr * 8192;
        const f16* bB = lds + cur * 32768 + 16384 + (wc >> 1) * 8192;
        const int brow = (wc & 1) * 64;
        const int ua = u + 1 < KT ? u + 1 : KT - 1;     // clamp: keep counts uniform
        const int ub = u + 2 < KT ? u + 2 : KT - 1;
        const int bufA_ = (u + 1) & 1, bufB_ = cur;     // (u+2)&1 == u&1
        f16x8 bf[4][2];
#pragma unroll
        for (int p = 0; p < 4; ++p) {
            f16x8 a[2][2];
            if (p == 0) {
#pragma unroll
                for (int j = 0; j < 4; ++j)
#pragma unroll
                    for (int ks = 0; ks < 2; ++ks)
                        bf[j][ks] = *(const f16x8*)&bB[(brow + j * 16 + rr) * 64 + ((ks * 4 + q + rr) & 7) * 8];
            }
#pragma unroll
            for (int fi = 0; fi < 2; ++fi)
#pragma unroll
                for (int ks = 0; ks < 2; ++ks)
                    a[fi][ks] = *(const f16x8*)&bA[((p * 2 + fi) * 16 + rr) * 64 + ((ks * 4 + q + rr) & 7) * 8];
            if      (p == 0) stageA(ua, 0, bufA_);
            else if (p == 1) stageA(ua, 1, bufA_);
            else if (p == 2) stageB(ub, 0, bufB_);
            else             stageB(ub, 1, bufB_);
            __builtin_amdgcn_s_barrier();
            asm volatile("s_waitcnt lgkmcnt(0)" ::: "memory");
            __builtin_amdgcn_sched_barrier(0);
            __builtin_amdgcn_s_setprio(1);
#pragma unroll
            for (int ks = 0; ks < 2; ++ks)
#pragma unroll
                for (int fi = 0; fi < 2; ++fi)
#pragma unroll
                    for (int j = 0; j < 4; ++j)
                        acc[p * 2 + fi][j] = __builtin_amdgcn_mfma_f32_16x16x32_f16(
                            a[fi][ks], bf[j][ks], acc[p * 2 + fi][j], 0, 0, 0);
            __builtin_amdgcn_s_setprio(0);
            if (p == 3) asm volatile("s_waitcnt vmcnt(4)" ::: "memory");
            __builtin_amdgcn_s_barrier();
        }
    }
    asm volatile("s_waitcnt vmcnt(0)" ::: "memory");     // drain DMA before exit

    // epilogue: row = m0 + wr*128 + i*16 + q*4 + r2, col = n0 + wc*64 + j*16 + rr
#pragma unroll
    for (int i = 0; i < 8; ++i)
#pragma unroll
        for (int r2 = 0; r2 < 4; ++r2) {
            const long row = m0 + wr * 128 + i * 16 + q * 4 + r2;
#pragma unroll
            for (int j = 0; j < 4; ++j)
                Cb[row * ldc + n0 + wc * 64 + j * 16 + rr] = (f16)acc[i][j][r2];
        }
}

// -------- 128x128 MFMA GEMM, 4 waves, XOR-swizzled k-chunks --------
// Counted-vmcnt 3-buffer pipeline (verified round-6): stage kt+2, compute
// kt%3, vmcnt(4)+s_barrier per K-step, no in-loop drain. LDS 48KB, 3 blk/CU.
// LEDGER: counted vmcnt is only valid over a loads-only VMEM window (rounds
// 8/9: persistent variants mixing epilogue stores into the window failed);
// these kernels end their block life after the epilogue -> safe.
// MODE 1: grid (264,1,4), XCD-chunked remap (264 = 8*33). i<136: compact
//         lower-triangle P' = exp(scale*QK^T), causal zero, f16 scalar stores.
//         i>=136: V^T projection blocks (Vt[b] = Wv^T x xh[b]).
// MODE 2: grid (8,16,4), XCD c <- rows {c,15-c}, long/short complementary
//         across the co-resident (bz,bz+2) pair -> 68 ktiles on every CU.
//         Row sums in-kernel via ones-MFMA on wn==0 waves; f32 scalar stores.
template <int MODE>
__global__ __launch_bounds__(256, 3)
void gemm128(const f16* __restrict__ A, int lda, long aStride,
             const f16* __restrict__ B, int ldb, long bStride,
             void* __restrict__ Cout, int ldc, long cStride,
             int ktiles, float scale,
             const f16* __restrict__ A2, const f16* __restrict__ B2,
             void* __restrict__ C2) {
    int bz = blockIdx.z;
    int m0, n0;
    const f16 *Ab, *Bb;
    char* Cb;
    bool proj = false;

    if (MODE == 1) {
        int x = blockIdx.x;
        int i = (x & 7) * 33 + (x >> 3);     // XCD-contiguous chunks, bijective
        if (i < 136) {                       // compact lower triangle
            float ff = sqrtf(8.f * (float)i + 1.f);
            int bm = (int)((ff - 1.f) * 0.5f);
            while ((bm + 1) * (bm + 2) / 2 <= i) ++bm;
            while (bm * (bm + 1) / 2 > i) --bm;
            int bn = i - bm * (bm + 1) / 2;
            m0 = bm * 128; n0 = bn * 128;
            Ab = A + (long)bz * aStride;
            Bb = B + (long)bz * bStride;
            Cb = (char*)Cout + (long)bz * cStride * sizeof(f16);
        } else {                             // V^T: Vt[b][h][t]
            proj = true;
            int vb = i - 136;                // 0..127
            m0 = (vb >> 4) * 128;            // h-tile (8)
            n0 = (vb & 15) * 128;            // t-tile (16)
            Ab = A2;                         // Wv^T rows, ld 1024
            Bb = B2 + (long)bz * 2048 * 1024;
            Cb = (char*)C2 + (long)bz * 1024 * 2048 * sizeof(f16);
            lda = 1024; ldb = 1024; ldc = 2048;
        }
    } else {
        int l = blockIdx.x + 8 * blockIdx.y; // grid (8,16): l in [0,128)
        int c = l & 7, idx = l >> 3;
        int bm = ((idx < 8) ^ (bz >= 2)) ? (15 - c) : c;   // complementary pair
        int bn = idx & 7;
        int lim = 4 * (bm + 1); if (lim < ktiles) ktiles = lim;
        m0 = bm * 128; n0 = bn * 128;
        Ab = A + (long)bz * aStride;
        Bb = B + (long)bz * bStride;
        Cb = (char*)Cout + (long)bz * cStride * sizeof(float);
    }

    __shared__ f16 lds[3 * 8192];    // 3 x [A:4096 f16 | B:4096 f16] = 48 KiB

    const int tid = threadIdx.x;
    const int wave = tid >> 6, lane = tid & 63;
    const int q = lane >> 4, rr = lane & 15;
    const int wm = (wave >> 1) * 64, wn = (wave & 1) * 64;

    const int kcs = (((tid & 3) - (lane >> 4)) & 3) * 8;   // f16 col within BK=32
    const f16* pA = Ab + (long)(m0 + (tid >> 2)) * lda + kcs;
    const f16* pB = Bb + (long)(n0 + (tid >> 2)) * ldb + kcs;

    auto stage = [&](int kt, int buf) {
        const int k0 = kt * 32;
        f16* lA = lds + buf * 8192 + wave * 512;           // + lane*16B by HW
        f16* lB = lds + buf * 8192 + 4096 + wave * 512;
#pragma unroll
        for (int it = 0; it < 2; ++it) {
            gld_lds16(pA + (long)it * 64 * lda + k0, lA + it * 2048);
            gld_lds16(pB + (long)it * 64 * ldb + k0, lB + it * 2048);
        }
    };

    const int slotf = ((q + (rr >> 2)) & 3) * 8;           // f16 col within row

    f32x4 acc[4][4] = {};
    f32x4 accs[4] = {};              // MODE 2: row sums (wn==0 waves only)
    f16x8 onef;
    const bool sumwave = (MODE == 2) && (wn == 0);
    if (MODE == 2) {
#pragma unroll
        for (int t = 0; t < 8; ++t) onef[t] = (f16)1.0f;
    }

    // prologue: tiles 0,1 in flight; vmcnt(4) -> tile0 landed (tile1's 4 fly).
    stage(0, 0);
    stage(1, 1);
    asm volatile("s_waitcnt vmcnt(4)" ::: "memory");
    __builtin_amdgcn_s_barrier();

    for (int kt = 0; kt < ktiles; ++kt) {
        const int cur = kt % 3;
        int nxt = kt + 2; if (nxt >= ktiles) nxt = ktiles - 1;  // clamp source
        stage(nxt, (kt + 2) % 3);    // issue BEFORE compute; 4 loads, uniform
        const f16* bufA = lds + cur * 8192;
        const f16* bufB = bufA + 4096;
        f16x8 af[4], bf[4];
#pragma unroll
        for (int i = 0; i < 4; ++i)
            af[i] = *(const f16x8*)&bufA[(wm + i * 16 + rr) * 32 + slotf];
#pragma unroll
        for (int j = 0; j < 4; ++j)
            bf[j] = *(const f16x8*)&bufB[(wn + j * 16 + rr) * 32 + slotf];
#pragma unroll
        for (int i = 0; i < 4; ++i) {
#pragma unroll
            for (int j = 0; j < 4; ++j)
                acc[i][j] = __builtin_amdgcn_mfma_f32_16x16x32_f16(af[i], bf[j], acc[i][j], 0, 0, 0);
            if (sumwave)             // wave-uniform branch: row sums of A (=P')
                accs[i] = __builtin_amdgcn_mfma_f32_16x16x32_f16(af[i], onef, accs[i], 0, 0, 0);
        }
        // tile kt+1's 4 loads landed; tile kt+2's 4 stay in flight. No drain.
        asm volatile("s_waitcnt vmcnt(4)" ::: "memory");
        __builtin_amdgcn_s_barrier();
    }
    asm volatile("s_waitcnt vmcnt(0)" ::: "memory");     // drain before LDS reuse/exit
    __builtin_amdgcn_s_barrier();

    // MODE 2: hand row sums to the wn==64 waves via LDS.
    float invr[4][4];
    if (MODE == 2) {
        float* rs = (float*)lds;     // 128 floats, local rows
        if (sumwave && rr == 0) {
#pragma unroll
            for (int i = 0; i < 4; ++i)
#pragma unroll
                for (int r2 = 0; r2 < 4; ++r2)
                    rs[wm + i * 16 + q * 4 + r2] = accs[i][r2];
        }
        __syncthreads();
#pragma unroll
        for (int i = 0; i < 4; ++i)
#pragma unroll
            for (int r2 = 0; r2 < 4; ++r2)
                invr[i][r2] = 1.0f / rs[wm + i * 16 + q * 4 + r2];
    }

    const float scl = (MODE == 1 && proj) ? 1.0f : scale;

    // epilogue: C/D layout col=lane&15, row=(lane>>4)*4+reg; scalar stores
#pragma unroll
    for (int i = 0; i < 4; ++i) {
#pragma unroll
        for (int r2 = 0; r2 < 4; ++r2) {
            const int row = wm + i * 16 + q * 4 + r2;       // local 0..127
#pragma unroll
            for (int j = 0; j < 4; ++j) {
                const int col = wn + j * 16 + rr;           // local 0..127
                float v = acc[i][j][r2] * scl;
                long idx = (long)(m0 + row) * ldc + n0 + col;
                if (MODE == 1) {
                    if (!proj) {
                        v = __expf(v);
                        if (n0 + col > m0 + row) v = 0.f;
                    }
                    ((f16*)Cb)[idx] = (f16)v;
                } else {
                    ((float*)Cb)[idx] = v * invr[i][r2];
                }
            }
        }
    }
}

// ---------------- launch ----------------
extern "C" void kernel_launch(void* const* d_in, const int* in_sizes, int n_in,
                              void* d_out, int out_size, void* d_ws, size_t ws_size,
                              hipStream_t stream) {
    (void)in_sizes; (void)n_in; (void)out_size; (void)ws_size;
    const float* x  = (const float*)d_in[0];
    const float* Wk = (const float*)d_in[1];
    const float* Wq = (const float*)d_in[2];
    const float* Wv = (const float*)d_in[3];
    float* out = (float*)d_out;

    const long MB = 1l << 20;
    char* ws = (char*)d_ws;
    f16*   qk   = (f16*)(ws);             // 32 MB: [4*2048][2048]  (Q cols 0-1023 | K cols 1024-2047)
    f16*   Vt   = (f16*)(ws + 32 * MB);   // 16 MB: [4][1024][2048] (V^T)
    f16*   P    = (f16*)(ws + 48 * MB);   // 32 MB: [4][2048][2048] unnormalized exp-scores
    f16*   xh   = (f16*)(ws + 81 * MB);   // 16 MB
    f16*   Wt   = (f16*)(ws + 97 * MB);   //  6 MB

    // converts, one launch
    cvt_fused<<<7168, 256, 0, stream>>>(x, xh, Wq, Wk, Wv, Wt);

    // QK projection, 256^2 8-phase, exactly 256 blocks (no dispatch tail)
    gemm256<<<dim3(256), 512, 0, stream>>>(xh, Wt, qk);

    // P' = exp(Q K^T / 32) causal-zeroed (136 triangle blocks) + V^T (128
    // blocks) per batch, one dispatch, XCD-chunked
    gemm128<1><<<dim3(264, 1, 4), 256, 0, stream>>>(qk, 2048, 2048l * 2048,
                                                    qk + 1024, 2048, 2048l * 2048,
                                                    P, 2048, 2048l * 2048, 32, 0.03125f,
                                                    Wt + 2l * 1024 * 1024, xh, Vt);
    // O = (P' V) / rowsum   (rowsum via in-kernel ones-MFMA; k clamped per row-block)
    gemm128<2><<<dim3(8, 16, 4), 256, 0, stream>>>(P, 2048, 2048l * 2048,
                                                   Vt, 2048, 1024l * 2048,
                                                   out, 1024, 2048l * 1024, 64, 1.0f,
                                                   nullptr, nullptr, nullptr);
}